// Round 5
// baseline (426.717 us; speedup 1.0000x reference)
//
#include <hip/hip_runtime.h>
#include <cstdint>
#include <cstddef>

#define H_  16
#define V_  8
#define DH_ 128
#define B_  4096
#define BT  32

#define LDW 136   // padded row stride (halves) for f16 LDS tiles

typedef _Float16 v8h __attribute__((ext_vector_type(8)));
typedef _Float16 v4h __attribute__((ext_vector_type(4)));
typedef float    v4f __attribute__((ext_vector_type(4)));

// ---------------------------------------------------------------------------
// Kernel A: MT16[h][dp][d] = sum_e Wq[e][d]*Wk[e][dp]      (f16, = M^T)
//           N216[h][e][dp] = sum_d Wo[e][d]*Wv[d][dp]      (f16, = Wo@Wv)
// Layouts chosen so fused-kernel B-fragments (k-contiguous per lane) are
// single ds_read_b128 from row-major LDS tiles.
// ---------------------------------------------------------------------------
__global__ __launch_bounds__(256) void precompute_MN(
    const float* __restrict__ Wq, const float* __restrict__ Wk,
    const float* __restrict__ Wv, const float* __restrict__ Wo,
    _Float16* __restrict__ MT16, _Float16* __restrict__ N216)
{
    const int bx    = blockIdx.x;
    const int which = bx & 1;
    const int h     = (bx >> 1) & 15;
    const int chunk = bx >> 5;                // 0..63
    const int tid   = threadIdx.x;
    const int col   = tid & 127;
    const int r     = chunk * 2 + (tid >> 7); // 0..127

    float acc = 0.f;
    if (which == 0) {
        const float* wq = Wq + h * DH_ * DH_;
        const float* wk = Wk + h * DH_ * DH_;
#pragma unroll 8
        for (int e = 0; e < DH_; ++e)
            acc += wq[e * DH_ + col] * wk[e * DH_ + r];   // coalesced * uniform
        MT16[(size_t)h * DH_ * DH_ + r * DH_ + col] = (_Float16)acc;
    } else {
        const float* wo = Wo + h * DH_ * DH_;
        const float* wv = Wv + h * DH_ * DH_;
#pragma unroll 8
        for (int d = 0; d < DH_; ++d)
            acc += wo[r * DH_ + d] * wv[d * DH_ + col];   // uniform * coalesced
        N216[(size_t)h * DH_ * DH_ + r * DH_ + col] = (_Float16)acc;
    }
}

// ---------------------------------------------------------------------------
// Kernel B: round-3 verified structure + qk stored as f16 in its OWN buffer.
//   LDS = w16 34816 + a16 8704 + qk16 8704 = 52224 B -> 3 blocks/CU (was 2).
//   No type-punning, no in-place overwrite: hazard graph identical to the
//   round-3 passing kernel (qk written before B2, read after B2).
//   phase1: qk(32x128) = iso16 @ M  via mfma_f32_16x16x32_f16 -> qk16 (f16)
//   middle: scores/softmax/ctx, view read once (coalesced, depth-1 prefetch)
//   phase3: out = ctx16 @ N2 via mfma
// ---------------------------------------------------------------------------
__global__ __launch_bounds__(256, 3) void fused_attn(
    const float* __restrict__ iso, const float* __restrict__ view,
    const float* __restrict__ pi,
    const _Float16* __restrict__ MT16, const _Float16* __restrict__ N216,
    float* __restrict__ out, float* __restrict__ attn_out)
{
    __shared__ __align__(16) _Float16 w16[128 * LDW];  // M^T, then N2 (B-operand)
    __shared__ __align__(16) _Float16 a16[BT * LDW];   // iso16, then ctx16 (A-operand)
    __shared__ __align__(16) _Float16 qk16[BT * LDW];  // qk (f16) for the middle

    const int tid = threadIdx.x;
    const int h   = blockIdx.x >> 7;            // 128 b-tiles per head
    const int b0  = (blockIdx.x & 127) * BT;

    const int w    = tid >> 6;                  // wave 0..3
    const int lane = tid & 63;
    const int rt   = w >> 1;                    // row-tile (16 rows)
    const int cb   = (w & 1) * 64;              // col base
    const int fr   = lane & 15;                 // fragment row/col
    const int kg   = lane >> 4;                 // k-group 0..3

    // ---- stage iso -> a16 (cvt f32->f16), MT16 -> w16
#pragma unroll
    for (int i = 0; i < 4; ++i) {
        const int idx = tid + i * 256;          // 1024 float4
        const int r   = idx >> 5, c4 = idx & 31;
        const float4 t = *(const float4*)(iso + ((size_t)(b0 + r) * H_ + h) * DH_ + c4 * 4);
        v4h ht; ht[0] = (_Float16)t.x; ht[1] = (_Float16)t.y;
                ht[2] = (_Float16)t.z; ht[3] = (_Float16)t.w;
        *(v4h*)&a16[r * LDW + c4 * 4] = ht;
    }
    {
        const _Float16* src = MT16 + (size_t)h * DH_ * DH_;
#pragma unroll
        for (int i = 0; i < 8; ++i) {
            const int idx = tid + i * 256;      // 2048 chunks of 8 halves
            *(v8h*)&w16[(idx >> 4) * LDW + (idx & 15) * 8] = *(const v8h*)(src + idx * 8);
        }
    }
    __syncthreads();

    // ---- phase 1: qk = iso @ M  (A=a16, B=w16 rows are M^T[d'][d])
    {
        v4f ac0 = {0,0,0,0}, ac1 = {0,0,0,0}, ac2 = {0,0,0,0}, ac3 = {0,0,0,0};
#pragma unroll
        for (int kt = 0; kt < 4; ++kt) {
            const int ko = kt * 32 + kg * 8;
            const v8h a  = *(const v8h*)&a16[(rt * 16 + fr) * LDW + ko];
            const v8h bf0 = *(const v8h*)&w16[(cb +  0 + fr) * LDW + ko];
            const v8h bf1 = *(const v8h*)&w16[(cb + 16 + fr) * LDW + ko];
            const v8h bf2 = *(const v8h*)&w16[(cb + 32 + fr) * LDW + ko];
            const v8h bf3 = *(const v8h*)&w16[(cb + 48 + fr) * LDW + ko];
            ac0 = __builtin_amdgcn_mfma_f32_16x16x32_f16(a, bf0, ac0, 0, 0, 0);
            ac1 = __builtin_amdgcn_mfma_f32_16x16x32_f16(a, bf1, ac1, 0, 0, 0);
            ac2 = __builtin_amdgcn_mfma_f32_16x16x32_f16(a, bf2, ac2, 0, 0, 0);
            ac3 = __builtin_amdgcn_mfma_f32_16x16x32_f16(a, bf3, ac3, 0, 0, 0);
        }
        // C/D layout: col = lane&15, row = (lane>>4)*4 + reg  (own buffer: no WAR)
#pragma unroll
        for (int g = 0; g < 4; ++g) {
            const int row = rt * 16 + kg * 4 + g;
            qk16[row * LDW + cb +  0 + fr] = (_Float16)ac0[g];
            qk16[row * LDW + cb + 16 + fr] = (_Float16)ac1[g];
            qk16[row * LDW + cb + 32 + fr] = (_Float16)ac2[g];
            qk16[row * LDW + cb + 48 + fr] = (_Float16)ac3[g];
        }
    }
    __syncthreads();    // qk visible; all reads of a16(iso)/w16(MT) done

    // ---- stage N216 -> w16 (latency hides under the middle phase)
    {
        const _Float16* src = N216 + (size_t)h * DH_ * DH_;
#pragma unroll
        for (int i = 0; i < 8; ++i) {
            const int idx = tid + i * 256;
            *(v8h*)&w16[(idx >> 4) * LDW + (idx & 15) * 8] = *(const v8h*)(src + idx * 8);
        }
    }

    // ---- middle: wave w owns rows 8w..8w+7. view read once, depth-1 prefetch.
    {
        const int hl  = lane >> 5;              // parity: lane half
        const int l32 = lane & 31;              // d-chunk (l32*4..+3)
        const float SC = 0.08838834764831845f;  // 1/sqrt(128)

        const float* vb = view + ((size_t)(b0 + w * 8) * H_ + h) * (V_ * DH_);
        float4 x0 = *(const float4*)(vb +   0 + lane * 4);
        float4 x1 = *(const float4*)(vb + 256 + lane * 4);
        float4 x2 = *(const float4*)(vb + 512 + lane * 4);
        float4 x3 = *(const float4*)(vb + 768 + lane * 4);

#pragma unroll
        for (int r = 0; r < 8; ++r) {
            const int row   = w * 8 + r;
            const size_t bh = (size_t)(b0 + row) * H_ + h;

            const v4h qh = *(const v4h*)&qk16[row * LDW + l32 * 4];
            const float q0 = (float)qh[0], q1 = (float)qh[1];
            const float q2 = (float)qh[2], q3 = (float)qh[3];
            // partial dots; half hl holds v = 2j + hl, d-chunk = l32*4
            float p0 = x0.x*q0 + x0.y*q1 + x0.z*q2 + x0.w*q3;
            float p1 = x1.x*q0 + x1.y*q1 + x1.z*q2 + x1.w*q3;
            float p2 = x2.x*q0 + x2.y*q1 + x2.z*q2 + x2.w*q3;
            float p3 = x3.x*q0 + x3.y*q1 + x3.z*q2 + x3.w*q3;

            // prefetch next row (keeps ~8KB/wave in flight toward HBM)
            float4 y0, y1, y2, y3;
            if (r < 7) {
                const float* vn = vb + H_ * V_ * DH_;
                y0 = *(const float4*)(vn +   0 + lane * 4);
                y1 = *(const float4*)(vn + 256 + lane * 4);
                y2 = *(const float4*)(vn + 512 + lane * 4);
                y3 = *(const float4*)(vn + 768 + lane * 4);
            }

            // reduce each dot over its 32-lane half
            p0 += __shfl_xor(p0, 1); p0 += __shfl_xor(p0, 2); p0 += __shfl_xor(p0, 4);
            p0 += __shfl_xor(p0, 8); p0 += __shfl_xor(p0, 16);
            p1 += __shfl_xor(p1, 1); p1 += __shfl_xor(p1, 2); p1 += __shfl_xor(p1, 4);
            p1 += __shfl_xor(p1, 8); p1 += __shfl_xor(p1, 16);
            p2 += __shfl_xor(p2, 1); p2 += __shfl_xor(p2, 2); p2 += __shfl_xor(p2, 4);
            p2 += __shfl_xor(p2, 8); p2 += __shfl_xor(p2, 16);
            p3 += __shfl_xor(p3, 1); p3 += __shfl_xor(p3, 2); p3 += __shfl_xor(p3, 4);
            p3 += __shfl_xor(p3, 8); p3 += __shfl_xor(p3, 16);
            // opposite-parity sums
            const float o0 = __shfl_xor(p0, 32);
            const float o1 = __shfl_xor(p1, 32);
            const float o2 = __shfl_xor(p2, 32);
            const float o3 = __shfl_xor(p3, 32);

            // softmax(s/sqrt(d)+log(pi+eps)) == (pi+eps)*exp(s/sqrt(d)-m) normalized
            const float4 pa = *(const float4*)(pi + bh * V_);
            const float4 pb = *(const float4*)(pi + bh * V_ + 4);
            const float pe0 = hl ? pa.y : pa.x,  po0 = hl ? pa.x : pa.y;
            const float pe1 = hl ? pa.w : pa.z,  po1 = hl ? pa.z : pa.w;
            const float pe2 = hl ? pb.y : pb.x,  po2 = hl ? pb.x : pb.y;
            const float pe3 = hl ? pb.w : pb.z,  po3 = hl ? pb.z : pb.w;

            const float s0 = p0 * SC, s1 = p1 * SC, s2 = p2 * SC, s3 = p3 * SC;
            const float t0 = o0 * SC, t1 = o1 * SC, t2 = o2 * SC, t3 = o3 * SC;
            const float m  = fmaxf(fmaxf(fmaxf(s0, s1), fmaxf(s2, s3)),
                                   fmaxf(fmaxf(t0, t1), fmaxf(t2, t3)));
            const float e0 = (pe0 + 1e-6f) * __expf(s0 - m);
            const float e1 = (pe1 + 1e-6f) * __expf(s1 - m);
            const float e2 = (pe2 + 1e-6f) * __expf(s2 - m);
            const float e3 = (pe3 + 1e-6f) * __expf(s3 - m);
            const float f0 = (po0 + 1e-6f) * __expf(t0 - m);
            const float f1 = (po1 + 1e-6f) * __expf(t1 - m);
            const float f2 = (po2 + 1e-6f) * __expf(t2 - m);
            const float f3 = (po3 + 1e-6f) * __expf(t3 - m);
            const float inv = 1.0f / (((e0 + e1) + (e2 + e3)) + ((f0 + f1) + (f2 + f3)));
            const float a0 = e0 * inv, a1 = e1 * inv, a2 = e2 * inv, a3 = e3 * inv;

            // ctx partial over own parity, cross-parity add
            float cx = a0 * x0.x + a1 * x1.x + a2 * x2.x + a3 * x3.x;
            float cy = a0 * x0.y + a1 * x1.y + a2 * x2.y + a3 * x3.y;
            float cz = a0 * x0.z + a1 * x1.z + a2 * x2.z + a3 * x3.z;
            float cw = a0 * x0.w + a1 * x1.w + a2 * x2.w + a3 * x3.w;
            cx += __shfl_xor(cx, 32);
            cy += __shfl_xor(cy, 32);
            cz += __shfl_xor(cz, 32);
            cw += __shfl_xor(cw, 32);
            if (lane < 32) {                    // ctx16 over dead iso16 (same as r3)
                v4h ch; ch[0] = (_Float16)cx; ch[1] = (_Float16)cy;
                        ch[2] = (_Float16)cz; ch[3] = (_Float16)cw;
                *(v4h*)&a16[row * LDW + l32 * 4] = ch;
            }
            if (l32 == 0) {                     // lanes 0 and 32
                float* ao = attn_out + bh * V_;
                ao[0 + hl] = a0; ao[2 + hl] = a1; ao[4 + hl] = a2; ao[6 + hl] = a3;
            }
            if (r < 7) { vb += H_ * V_ * DH_; x0 = y0; x1 = y1; x2 = y2; x3 = y3; }
        }
    }
    __syncthreads();    // ctx16 + N216 staged

    // ---- phase 3: out = ctx @ N2  (B rows are N2[e][d'] -> k=d' contiguous)
    {
        v4f bc0 = {0,0,0,0}, bc1 = {0,0,0,0}, bc2 = {0,0,0,0}, bc3 = {0,0,0,0};
#pragma unroll
        for (int kt = 0; kt < 4; ++kt) {
            const int ko = kt * 32 + kg * 8;
            const v8h a  = *(const v8h*)&a16[(rt * 16 + fr) * LDW + ko];
            const v8h bf0 = *(const v8h*)&w16[(cb +  0 + fr) * LDW + ko];
            const v8h bf1 = *(const v8h*)&w16[(cb + 16 + fr) * LDW + ko];
            const v8h bf2 = *(const v8h*)&w16[(cb + 32 + fr) * LDW + ko];
            const v8h bf3 = *(const v8h*)&w16[(cb + 48 + fr) * LDW + ko];
            bc0 = __builtin_amdgcn_mfma_f32_16x16x32_f16(a, bf0, bc0, 0, 0, 0);
            bc1 = __builtin_amdgcn_mfma_f32_16x16x32_f16(a, bf1, bc1, 0, 0, 0);
            bc2 = __builtin_amdgcn_mfma_f32_16x16x32_f16(a, bf2, bc2, 0, 0, 0);
            bc3 = __builtin_amdgcn_mfma_f32_16x16x32_f16(a, bf3, bc3, 0, 0, 0);
        }
#pragma unroll
        for (int g = 0; g < 4; ++g) {
            float* op = out + (size_t)(b0 + rt * 16 + kg * 4 + g) * (H_ * DH_) + h * DH_;
            op[cb +  0 + fr] = bc0[g];
            op[cb + 16 + fr] = bc1[g];
            op[cb + 32 + fr] = bc2[g];
            op[cb + 48 + fr] = bc3[g];
        }
    }
}

// ---------------------------------------------------------------------------
extern "C" void kernel_launch(void* const* d_in, const int* in_sizes, int n_in,
                              void* d_out, int out_size, void* d_ws, size_t ws_size,
                              hipStream_t stream)
{
    const float* iso  = (const float*)d_in[0];   // [B,H,DH]
    const float* view = (const float*)d_in[1];   // [B,H,V,DH]
    const float* pi   = (const float*)d_in[2];   // [B,H,V]
    const float* Wq   = (const float*)d_in[3];   // [H,DH,DH]
    const float* Wk   = (const float*)d_in[4];
    const float* Wv   = (const float*)d_in[5];
    const float* Wo   = (const float*)d_in[6];

    float* out  = (float*)d_out;                           // [B,H,DH]
    float* attn = out + (size_t)B_ * H_ * DH_;             // [B,H,V]

    _Float16* MT16 = (_Float16*)d_ws;                      // 512 KB
    _Float16* N216 = MT16 + (size_t)H_ * DH_ * DH_;        // 512 KB

    hipLaunchKernelGGL(precompute_MN, dim3(2048), dim3(256), 0, stream,
                       Wq, Wk, Wv, Wo, MT16, N216);
    hipLaunchKernelGGL(fused_attn, dim3(H_ * (B_ / BT)), dim3(256), 0, stream,
                       iso, view, pi, MT16, N216, out, attn);
}

// Round 7
// 425.911 us; speedup vs baseline: 1.0019x; 1.0019x over previous
//
#include <hip/hip_runtime.h>
#include <cstdint>
#include <cstddef>

#define H_  16
#define V_  8
#define DH_ 128
#define B_  4096
#define BT  32

#define LDW 136   // padded row stride (halves) for f16 LDS tiles

typedef _Float16 v8h __attribute__((ext_vector_type(8)));
typedef _Float16 v4h __attribute__((ext_vector_type(4)));
typedef float    v4f __attribute__((ext_vector_type(4)));

// ---------------------------------------------------------------------------
// Kernel A: MT16[h][dp][d] = sum_e Wq[e][d]*Wk[e][dp]      (f16, = M^T)
//           N216[h][e][dp] = sum_d Wo[e][d]*Wv[d][dp]      (f16, = Wo@Wv)
// Layouts chosen so fused-kernel B-fragments (k-contiguous per lane) are
// single ds_read_b128 from row-major LDS tiles.
// ---------------------------------------------------------------------------
__global__ __launch_bounds__(256) void precompute_MN(
    const float* __restrict__ Wq, const float* __restrict__ Wk,
    const float* __restrict__ Wv, const float* __restrict__ Wo,
    _Float16* __restrict__ MT16, _Float16* __restrict__ N216)
{
    const int bx    = blockIdx.x;
    const int which = bx & 1;
    const int h     = (bx >> 1) & 15;
    const int chunk = bx >> 5;                // 0..63
    const int tid   = threadIdx.x;
    const int col   = tid & 127;
    const int r     = chunk * 2 + (tid >> 7); // 0..127

    float acc = 0.f;
    if (which == 0) {
        const float* wq = Wq + h * DH_ * DH_;
        const float* wk = Wk + h * DH_ * DH_;
#pragma unroll 8
        for (int e = 0; e < DH_; ++e)
            acc += wq[e * DH_ + col] * wk[e * DH_ + r];   // coalesced * uniform
        MT16[(size_t)h * DH_ * DH_ + r * DH_ + col] = (_Float16)acc;
    } else {
        const float* wo = Wo + h * DH_ * DH_;
        const float* wv = Wv + h * DH_ * DH_;
#pragma unroll 8
        for (int d = 0; d < DH_; ++d)
            acc += wo[r * DH_ + d] * wv[d * DH_ + col];   // uniform * coalesced
        N216[(size_t)h * DH_ * DH_ + r * DH_ + col] = (_Float16)acc;
    }
}

// ---------------------------------------------------------------------------
// Kernel B: verified round-5 structure (exact revert; depth-1 prefetch).
//   LDS = w16 34816 + a16 8704 + qk16 8704 = 52224 B -> 3 blocks/CU.
//   No type-punning, no in-place overwrite, no depth-2 prefetch (twice-failed).
//   phase1: qk(32x128) = iso16 @ M  via mfma_f32_16x16x32_f16 -> qk16 (f16)
//   middle: scores/softmax/ctx, view read once (coalesced, depth-1 prefetch)
//   phase3: out = ctx16 @ N2 via mfma
// ---------------------------------------------------------------------------
__global__ __launch_bounds__(256, 3) void fused_attn(
    const float* __restrict__ iso, const float* __restrict__ view,
    const float* __restrict__ pi,
    const _Float16* __restrict__ MT16, const _Float16* __restrict__ N216,
    float* __restrict__ out, float* __restrict__ attn_out)
{
    __shared__ __align__(16) _Float16 w16[128 * LDW];  // M^T, then N2 (B-operand)
    __shared__ __align__(16) _Float16 a16[BT * LDW];   // iso16, then ctx16 (A-operand)
    __shared__ __align__(16) _Float16 qk16[BT * LDW];  // qk (f16) for the middle

    const int tid = threadIdx.x;
    const int h   = blockIdx.x >> 7;            // 128 b-tiles per head
    const int b0  = (blockIdx.x & 127) * BT;

    const int w    = tid >> 6;                  // wave 0..3
    const int lane = tid & 63;
    const int rt   = w >> 1;                    // row-tile (16 rows)
    const int cb   = (w & 1) * 64;              // col base
    const int fr   = lane & 15;                 // fragment row/col
    const int kg   = lane >> 4;                 // k-group 0..3

    // ---- stage iso -> a16 (cvt f32->f16), MT16 -> w16
#pragma unroll
    for (int i = 0; i < 4; ++i) {
        const int idx = tid + i * 256;          // 1024 float4
        const int r   = idx >> 5, c4 = idx & 31;
        const float4 t = *(const float4*)(iso + ((size_t)(b0 + r) * H_ + h) * DH_ + c4 * 4);
        v4h ht; ht[0] = (_Float16)t.x; ht[1] = (_Float16)t.y;
                ht[2] = (_Float16)t.z; ht[3] = (_Float16)t.w;
        *(v4h*)&a16[r * LDW + c4 * 4] = ht;
    }
    {
        const _Float16* src = MT16 + (size_t)h * DH_ * DH_;
#pragma unroll
        for (int i = 0; i < 8; ++i) {
            const int idx = tid + i * 256;      // 2048 chunks of 8 halves
            *(v8h*)&w16[(idx >> 4) * LDW + (idx & 15) * 8] = *(const v8h*)(src + idx * 8);
        }
    }
    __syncthreads();

    // ---- phase 1: qk = iso @ M  (A=a16, B=w16 rows are M^T[d'][d])
    {
        v4f ac0 = {0,0,0,0}, ac1 = {0,0,0,0}, ac2 = {0,0,0,0}, ac3 = {0,0,0,0};
#pragma unroll
        for (int kt = 0; kt < 4; ++kt) {
            const int ko = kt * 32 + kg * 8;
            const v8h a  = *(const v8h*)&a16[(rt * 16 + fr) * LDW + ko];
            const v8h bf0 = *(const v8h*)&w16[(cb +  0 + fr) * LDW + ko];
            const v8h bf1 = *(const v8h*)&w16[(cb + 16 + fr) * LDW + ko];
            const v8h bf2 = *(const v8h*)&w16[(cb + 32 + fr) * LDW + ko];
            const v8h bf3 = *(const v8h*)&w16[(cb + 48 + fr) * LDW + ko];
            ac0 = __builtin_amdgcn_mfma_f32_16x16x32_f16(a, bf0, ac0, 0, 0, 0);
            ac1 = __builtin_amdgcn_mfma_f32_16x16x32_f16(a, bf1, ac1, 0, 0, 0);
            ac2 = __builtin_amdgcn_mfma_f32_16x16x32_f16(a, bf2, ac2, 0, 0, 0);
            ac3 = __builtin_amdgcn_mfma_f32_16x16x32_f16(a, bf3, ac3, 0, 0, 0);
        }
        // C/D layout: col = lane&15, row = (lane>>4)*4 + reg  (own buffer: no WAR)
#pragma unroll
        for (int g = 0; g < 4; ++g) {
            const int row = rt * 16 + kg * 4 + g;
            qk16[row * LDW + cb +  0 + fr] = (_Float16)ac0[g];
            qk16[row * LDW + cb + 16 + fr] = (_Float16)ac1[g];
            qk16[row * LDW + cb + 32 + fr] = (_Float16)ac2[g];
            qk16[row * LDW + cb + 48 + fr] = (_Float16)ac3[g];
        }
    }
    __syncthreads();    // qk visible; all reads of a16(iso)/w16(MT) done

    // ---- stage N216 -> w16 (latency hides under the middle phase)
    {
        const _Float16* src = N216 + (size_t)h * DH_ * DH_;
#pragma unroll
        for (int i = 0; i < 8; ++i) {
            const int idx = tid + i * 256;
            *(v8h*)&w16[(idx >> 4) * LDW + (idx & 15) * 8] = *(const v8h*)(src + idx * 8);
        }
    }

    // ---- middle: wave w owns rows 8w..8w+7. view read once, depth-1 prefetch.
    {
        const int hl  = lane >> 5;              // parity: lane half
        const int l32 = lane & 31;              // d-chunk (l32*4..+3)
        const float SC = 0.08838834764831845f;  // 1/sqrt(128)

        const float* vb = view + ((size_t)(b0 + w * 8) * H_ + h) * (V_ * DH_);
        float4 x0 = *(const float4*)(vb +   0 + lane * 4);
        float4 x1 = *(const float4*)(vb + 256 + lane * 4);
        float4 x2 = *(const float4*)(vb + 512 + lane * 4);
        float4 x3 = *(const float4*)(vb + 768 + lane * 4);

#pragma unroll
        for (int r = 0; r < 8; ++r) {
            const int row   = w * 8 + r;
            const size_t bh = (size_t)(b0 + row) * H_ + h;

            const v4h qh = *(const v4h*)&qk16[row * LDW + l32 * 4];
            const float q0 = (float)qh[0], q1 = (float)qh[1];
            const float q2 = (float)qh[2], q3 = (float)qh[3];
            // partial dots; half hl holds v = 2j + hl, d-chunk = l32*4
            float p0 = x0.x*q0 + x0.y*q1 + x0.z*q2 + x0.w*q3;
            float p1 = x1.x*q0 + x1.y*q1 + x1.z*q2 + x1.w*q3;
            float p2 = x2.x*q0 + x2.y*q1 + x2.z*q2 + x2.w*q3;
            float p3 = x3.x*q0 + x3.y*q1 + x3.z*q2 + x3.w*q3;

            // prefetch next row (keeps ~8KB/wave in flight toward HBM)
            float4 y0, y1, y2, y3;
            if (r < 7) {
                const float* vn = vb + H_ * V_ * DH_;
                y0 = *(const float4*)(vn +   0 + lane * 4);
                y1 = *(const float4*)(vn + 256 + lane * 4);
                y2 = *(const float4*)(vn + 512 + lane * 4);
                y3 = *(const float4*)(vn + 768 + lane * 4);
            }

            // reduce each dot over its 32-lane half
            p0 += __shfl_xor(p0, 1); p0 += __shfl_xor(p0, 2); p0 += __shfl_xor(p0, 4);
            p0 += __shfl_xor(p0, 8); p0 += __shfl_xor(p0, 16);
            p1 += __shfl_xor(p1, 1); p1 += __shfl_xor(p1, 2); p1 += __shfl_xor(p1, 4);
            p1 += __shfl_xor(p1, 8); p1 += __shfl_xor(p1, 16);
            p2 += __shfl_xor(p2, 1); p2 += __shfl_xor(p2, 2); p2 += __shfl_xor(p2, 4);
            p2 += __shfl_xor(p2, 8); p2 += __shfl_xor(p2, 16);
            p3 += __shfl_xor(p3, 1); p3 += __shfl_xor(p3, 2); p3 += __shfl_xor(p3, 4);
            p3 += __shfl_xor(p3, 8); p3 += __shfl_xor(p3, 16);
            // opposite-parity sums
            const float o0 = __shfl_xor(p0, 32);
            const float o1 = __shfl_xor(p1, 32);
            const float o2 = __shfl_xor(p2, 32);
            const float o3 = __shfl_xor(p3, 32);

            // softmax(s/sqrt(d)+log(pi+eps)) == (pi+eps)*exp(s/sqrt(d)-m) normalized
            const float4 pa = *(const float4*)(pi + bh * V_);
            const float4 pb = *(const float4*)(pi + bh * V_ + 4);
            const float pe0 = hl ? pa.y : pa.x,  po0 = hl ? pa.x : pa.y;
            const float pe1 = hl ? pa.w : pa.z,  po1 = hl ? pa.z : pa.w;
            const float pe2 = hl ? pb.y : pb.x,  po2 = hl ? pb.x : pb.y;
            const float pe3 = hl ? pb.w : pb.z,  po3 = hl ? pb.z : pb.w;

            const float s0 = p0 * SC, s1 = p1 * SC, s2 = p2 * SC, s3 = p3 * SC;
            const float t0 = o0 * SC, t1 = o1 * SC, t2 = o2 * SC, t3 = o3 * SC;
            const float m  = fmaxf(fmaxf(fmaxf(s0, s1), fmaxf(s2, s3)),
                                   fmaxf(fmaxf(t0, t1), fmaxf(t2, t3)));
            const float e0 = (pe0 + 1e-6f) * __expf(s0 - m);
            const float e1 = (pe1 + 1e-6f) * __expf(s1 - m);
            const float e2 = (pe2 + 1e-6f) * __expf(s2 - m);
            const float e3 = (pe3 + 1e-6f) * __expf(s3 - m);
            const float f0 = (po0 + 1e-6f) * __expf(t0 - m);
            const float f1 = (po1 + 1e-6f) * __expf(t1 - m);
            const float f2 = (po2 + 1e-6f) * __expf(t2 - m);
            const float f3 = (po3 + 1e-6f) * __expf(t3 - m);
            const float inv = 1.0f / (((e0 + e1) + (e2 + e3)) + ((f0 + f1) + (f2 + f3)));
            const float a0 = e0 * inv, a1 = e1 * inv, a2 = e2 * inv, a3 = e3 * inv;

            // ctx partial over own parity, cross-parity add
            float cx = a0 * x0.x + a1 * x1.x + a2 * x2.x + a3 * x3.x;
            float cy = a0 * x0.y + a1 * x1.y + a2 * x2.y + a3 * x3.y;
            float cz = a0 * x0.z + a1 * x1.z + a2 * x2.z + a3 * x3.z;
            float cw = a0 * x0.w + a1 * x1.w + a2 * x2.w + a3 * x3.w;
            cx += __shfl_xor(cx, 32);
            cy += __shfl_xor(cy, 32);
            cz += __shfl_xor(cz, 32);
            cw += __shfl_xor(cw, 32);
            if (lane < 32) {                    // ctx16 over dead iso16 (same as r3)
                v4h ch; ch[0] = (_Float16)cx; ch[1] = (_Float16)cy;
                        ch[2] = (_Float16)cz; ch[3] = (_Float16)cw;
                *(v4h*)&a16[row * LDW + l32 * 4] = ch;
            }
            if (l32 == 0) {                     // lanes 0 and 32
                float* ao = attn_out + bh * V_;
                ao[0 + hl] = a0; ao[2 + hl] = a1; ao[4 + hl] = a2; ao[6 + hl] = a3;
            }
            if (r < 7) { vb += H_ * V_ * DH_; x0 = y0; x1 = y1; x2 = y2; x3 = y3; }
        }
    }
    __syncthreads();    // ctx16 + N216 staged

    // ---- phase 3: out = ctx @ N2  (B rows are N2[e][d'] -> k=d' contiguous)
    {
        v4f bc0 = {0,0,0,0}, bc1 = {0,0,0,0}, bc2 = {0,0,0,0}, bc3 = {0,0,0,0};
#pragma unroll
        for (int kt = 0; kt < 4; ++kt) {
            const int ko = kt * 32 + kg * 8;
            const v8h a  = *(const v8h*)&a16[(rt * 16 + fr) * LDW + ko];
            const v8h bf0 = *(const v8h*)&w16[(cb +  0 + fr) * LDW + ko];
            const v8h bf1 = *(const v8h*)&w16[(cb + 16 + fr) * LDW + ko];
            const v8h bf2 = *(const v8h*)&w16[(cb + 32 + fr) * LDW + ko];
            const v8h bf3 = *(const v8h*)&w16[(cb + 48 + fr) * LDW + ko];
            bc0 = __builtin_amdgcn_mfma_f32_16x16x32_f16(a, bf0, bc0, 0, 0, 0);
            bc1 = __builtin_amdgcn_mfma_f32_16x16x32_f16(a, bf1, bc1, 0, 0, 0);
            bc2 = __builtin_amdgcn_mfma_f32_16x16x32_f16(a, bf2, bc2, 0, 0, 0);
            bc3 = __builtin_amdgcn_mfma_f32_16x16x32_f16(a, bf3, bc3, 0, 0, 0);
        }
#pragma unroll
        for (int g = 0; g < 4; ++g) {
            float* op = out + (size_t)(b0 + rt * 16 + kg * 4 + g) * (H_ * DH_) + h * DH_;
            op[cb +  0 + fr] = bc0[g];
            op[cb + 16 + fr] = bc1[g];
            op[cb + 32 + fr] = bc2[g];
            op[cb + 48 + fr] = bc3[g];
        }
    }
}

// ---------------------------------------------------------------------------
extern "C" void kernel_launch(void* const* d_in, const int* in_sizes, int n_in,
                              void* d_out, int out_size, void* d_ws, size_t ws_size,
                              hipStream_t stream)
{
    const float* iso  = (const float*)d_in[0];   // [B,H,DH]
    const float* view = (const float*)d_in[1];   // [B,H,V,DH]
    const float* pi   = (const float*)d_in[2];   // [B,H,V]
    const float* Wq   = (const float*)d_in[3];   // [H,DH,DH]
    const float* Wk   = (const float*)d_in[4];
    const float* Wv   = (const float*)d_in[5];
    const float* Wo   = (const float*)d_in[6];

    float* out  = (float*)d_out;                           // [B,H,DH]
    float* attn = out + (size_t)B_ * H_ * DH_;             // [B,H,V]

    _Float16* MT16 = (_Float16*)d_ws;                      // 512 KB
    _Float16* N216 = MT16 + (size_t)H_ * DH_ * DH_;        // 512 KB

    hipLaunchKernelGGL(precompute_MN, dim3(2048), dim3(256), 0, stream,
                       Wq, Wk, Wv, Wo, MT16, N216);
    hipLaunchKernelGGL(fused_attn, dim3(H_ * (B_ / BT)), dim3(256), 0, stream,
                       iso, view, pi, MT16, N216, out, attn);
}